// Round 1
// baseline (130.105 us; speedup 1.0000x reference)
//
#include <hip/hip_runtime.h>

#define C 128
#define CRED 32
#define K 7
#define KK 49
#define H 56
#define W 56
#define P (H*W)        // 3136
#define B 8
#define NPIX (B*P)     // 25088
#define BN_EPS 1e-5

// ws layout (floats)
#define T_SIZE (B*CRED*P)          // 802816 floats
#define SCALE_OFF T_SIZE
#define SHIFT_OFF (T_SIZE + CRED)

// ---------------- kernel 1: t[b,r,p] = sum_c w1[r,c]*x[b,c,p] + b1[r] ----------------
__global__ __launch_bounds__(256) void k1_conv1(const float* __restrict__ x,
                                                const float* __restrict__ w1,
                                                const float* __restrict__ b1,
                                                float* __restrict__ t) {
    __shared__ float s_w1t[C * CRED];   // [c][r]
    int tid = threadIdx.x;
    for (int i = tid; i < C * CRED; i += 256) {
        int c = i >> 5, r = i & 31;
        s_w1t[i] = w1[r * C + c];
    }
    __syncthreads();
    int b = blockIdx.y;
    int p = blockIdx.x * 256 + tid;
    if (p >= P) return;
    float acc[CRED];
#pragma unroll
    for (int r = 0; r < CRED; ++r) acc[r] = 0.f;
    const float* xb = x + (size_t)b * C * P + p;
    for (int c = 0; c < C; ++c) {
        float xv = xb[(size_t)c * P];
#pragma unroll
        for (int r = 0; r < CRED; ++r)
            acc[r] = fmaf(s_w1t[c * CRED + r], xv, acc[r]);
    }
    float* tb = t + (size_t)b * CRED * P + p;
#pragma unroll
    for (int r = 0; r < CRED; ++r)
        tb[(size_t)r * P] = acc[r] + b1[r];
}

// ---------------- kernel 2: BN batch stats -> scale/shift per channel ----------------
__global__ __launch_bounds__(256) void k2_bnstats(const float* __restrict__ t,
                                                  const float* __restrict__ gamma,
                                                  const float* __restrict__ beta,
                                                  float* __restrict__ scale,
                                                  float* __restrict__ shift) {
    int r = blockIdx.x;
    int tid = threadIdx.x;
    double s = 0.0, s2 = 0.0;
    for (int i = tid; i < NPIX; i += 256) {
        int b = i / P, p = i - b * P;
        float v = t[((size_t)b * CRED + r) * P + p];
        s += v;
        s2 += (double)v * v;
    }
    __shared__ double ls[256], ls2[256];
    ls[tid] = s; ls2[tid] = s2;
    __syncthreads();
    for (int off = 128; off > 0; off >>= 1) {
        if (tid < off) { ls[tid] += ls[tid + off]; ls2[tid] += ls2[tid + off]; }
        __syncthreads();
    }
    if (tid == 0) {
        double mean = ls[0] / NPIX;
        double var = ls2[0] / NPIX - mean * mean;
        double sc = (double)gamma[r] / sqrt(var + BN_EPS);
        scale[r] = (float)sc;
        shift[r] = (float)((double)beta[r] - mean * sc);
    }
}

// ------- kernel 3: fused kern generation + involution. block = (h, b, zhalf) -------
// zhalf selects channels [z*64, z*64+64)
__global__ __launch_bounds__(256) void k3_involution(const float* __restrict__ x,
                                                     const float* __restrict__ t,
                                                     const float* __restrict__ scale,
                                                     const float* __restrict__ shift,
                                                     const float* __restrict__ w2,
                                                     const float* __restrict__ b2,
                                                     float* __restrict__ out) {
    int h = blockIdx.x;
    int b = blockIdx.y;
    int z = blockIdx.z;
    int tid = threadIdx.x;

    __shared__ float s_w2[KK * CRED];
    __shared__ float s_t[CRED][W];
    __shared__ float s_kern[KK][W];
    __shared__ float s_x[4][K][64];

    for (int i = tid; i < KK * CRED; i += 256) s_w2[i] = w2[i];
    for (int i = tid; i < CRED * W; i += 256) {
        int r = i / W, w = i - r * W;
        float v = t[((size_t)b * CRED + r) * P + h * W + w];
        v = fmaf(v, scale[r], shift[r]);
        s_t[r][w] = fmaxf(v, 0.f);
    }
    __syncthreads();

    // kern[k][w] = b2[k] + sum_r w2[k,r] * relu_t[r][w]
    for (int i = tid; i < KK * W; i += 256) {
        int k = i / W, w = i - k * W;
        float acc = b2[k];
#pragma unroll
        for (int r = 0; r < CRED; ++r)
            acc = fmaf(s_w2[k * CRED + r], s_t[r][w], acc);
        s_kern[k][w] = acc;
    }
    __syncthreads();

    // each thread owns (c4, w); preload its 49 kern values into registers
    int w = tid % W;          // 0..55
    int c4 = tid / W;         // 0..4 (c4==4 -> idle in compute)
    float kr[KK];
#pragma unroll
    for (int k = 0; k < KK; ++k) kr[k] = s_kern[k][w];

    int cbase = z * (C / 2);
    for (int cg = cbase; cg < cbase + C / 2; cg += 4) {
        // stage x halo tile for 4 channels: rows h-3..h+3, cols -3..60
        for (int i = tid; i < 4 * K * 64; i += 256) {
            int col = i & 63;
            int rc = i >> 6;          // 0..27
            int cc = rc / K;
            int row = rc - cc * K;
            int hh = h - 3 + row;
            int ww = col - 3;
            float v = 0.f;
            if ((unsigned)hh < H && (unsigned)ww < W)
                v = x[(((size_t)b * C + cg + cc) * H + hh) * W + ww];
            s_x[cc][row][col] = v;
        }
        __syncthreads();
        if (tid < 4 * W) {
            float acc = 0.f;
#pragma unroll
            for (int i = 0; i < K; ++i)
#pragma unroll
                for (int j = 0; j < K; ++j)
                    acc = fmaf(kr[i * K + j], s_x[c4][i][w + j], acc);
            out[(((size_t)b * C + cg + c4) * H + h) * W + w] = acc;
        }
        __syncthreads();
    }
}

extern "C" void kernel_launch(void* const* d_in, const int* in_sizes, int n_in,
                              void* d_out, int out_size, void* d_ws, size_t ws_size,
                              hipStream_t stream) {
    const float* x     = (const float*)d_in[0];
    const float* w1    = (const float*)d_in[1];
    const float* b1    = (const float*)d_in[2];
    const float* gamma = (const float*)d_in[3];
    const float* beta  = (const float*)d_in[4];
    const float* w2    = (const float*)d_in[5];
    const float* b2    = (const float*)d_in[6];
    float* out = (float*)d_out;
    float* ws  = (float*)d_ws;

    float* t     = ws;
    float* scale = ws + SCALE_OFF;
    float* shift = ws + SHIFT_OFF;

    dim3 g1((P + 255) / 256, B);
    k1_conv1<<<g1, 256, 0, stream>>>(x, w1, b1, t);
    k2_bnstats<<<CRED, 256, 0, stream>>>(t, gamma, beta, scale, shift);
    dim3 g3(H, B, 2);
    k3_involution<<<g3, 256, 0, stream>>>(x, t, scale, shift, w2, b2, out);
}

// Round 2
// 69.519 us; speedup vs baseline: 1.8715x; 1.8715x over previous
//
#include <hip/hip_runtime.h>

#define C 128
#define CRED 32
#define K 7
#define KK 49
#define H 56
#define W 56
#define P (H*W)        // 3136
#define B 8
#define NPIX (B*P)     // 25088
#define BN_EPS 1e-5

// ---------------- fast-path ws layout (floats) ----------------
#define T_OFF 0
#define T_SIZE (B*CRED*P)                 // 802816
#define KERN_OFF (T_OFF + T_SIZE)         // 802816
#define KERN_SIZE (B*KK*P)                // 1229312
#define NBLK_A 200
#define PSUM_OFF (KERN_OFF + KERN_SIZE)   // 2032128
#define PSQ_OFF (PSUM_OFF + NBLK_A*CRED)
#define SS_OFF  (PSQ_OFF + NBLK_A*CRED)
#define SCALE_OFF SS_OFF
#define SHIFT_OFF (SS_OFF + CRED)
#define WS_NEED ((size_t)(SHIFT_OFF + CRED) * sizeof(float))

// fallback (round-1) layout
#define FB_SCALE_OFF T_SIZE
#define FB_SHIFT_OFF (T_SIZE + CRED)

// ============ kA: t = w1*x + b1  (writes t) + per-block BN partial sums ============
__global__ __launch_bounds__(256) void kA_conv1(const float* __restrict__ x,
                                                const float* __restrict__ w1,
                                                const float* __restrict__ b1,
                                                float* __restrict__ ws) {
    __shared__ float s_w1t[C * CRED];   // [c][r]
    __shared__ float s_red[4][16];
    __shared__ float s_red2[4][16];
    int tid = threadIdx.x;
    for (int i = tid; i < C * CRED; i += 256) {
        int c = i >> 5, r = i & 31;
        s_w1t[i] = w1[r * C + c];
    }
    __syncthreads();
    int b = blockIdx.y;
    int p = blockIdx.x * 128 + (tid & 127);
    int rh = tid >> 7;                  // 0/1 -> r in [rh*16, rh*16+16)
    bool valid = p < P;
    float acc[16];
#pragma unroll
    for (int j = 0; j < 16; ++j) acc[j] = 0.f;
    const float* xb = x + (size_t)b * C * P + p;
    if (valid) {
        for (int c = 0; c < C; ++c) {
            float xv = xb[(size_t)c * P];
#pragma unroll
            for (int j = 0; j < 16; ++j)
                acc[j] = fmaf(s_w1t[c * CRED + rh * 16 + j], xv, acc[j]);
        }
    }
    float* t = ws + T_OFF;
#pragma unroll
    for (int j = 0; j < 16; ++j) {
        float v = acc[j] + b1[rh * 16 + j];
        acc[j] = valid ? v : 0.f;
        if (valid) t[((size_t)b * CRED + rh * 16 + j) * P + p] = v;
    }
    int wid = tid >> 6;
#pragma unroll
    for (int j = 0; j < 16; ++j) {
        float s1 = acc[j], s2 = acc[j] * acc[j];
#pragma unroll
        for (int off = 32; off; off >>= 1) {
            s1 += __shfl_xor(s1, off);
            s2 += __shfl_xor(s2, off);
        }
        if ((tid & 63) == 0) { s_red[wid][j] = s1; s_red2[wid][j] = s2; }
    }
    __syncthreads();
    if (tid < CRED) {
        int r = tid, j = r & 15, pr = r >> 4;   // waves {0,1}->r<16, {2,3}->r>=16
        float s1 = s_red[pr * 2][j] + s_red[pr * 2 + 1][j];
        float s2 = s_red2[pr * 2][j] + s_red2[pr * 2 + 1][j];
        int blk = b * 25 + blockIdx.x;
        ws[PSUM_OFF + blk * CRED + r] = s1;
        ws[PSQ_OFF + blk * CRED + r] = s2;
    }
}

// ============ kB: finalize BN stats -> scale/shift (1 block, deterministic) ============
__global__ __launch_bounds__(256) void kB_bnfin(const float* __restrict__ gamma,
                                                const float* __restrict__ beta,
                                                float* __restrict__ ws) {
    __shared__ double sd1[8][CRED];
    __shared__ double sd2[8][CRED];
    int tid = threadIdx.x;
    int r = tid & 31, g = tid >> 5;
    double s1 = 0.0, s2 = 0.0;
    for (int i = g * 25; i < g * 25 + 25; ++i) {
        s1 += (double)ws[PSUM_OFF + i * CRED + r];
        s2 += (double)ws[PSQ_OFF + i * CRED + r];
    }
    sd1[g][r] = s1; sd2[g][r] = s2;
    __syncthreads();
    if (tid < CRED) {
        double S1 = 0.0, S2 = 0.0;
        for (int gg = 0; gg < 8; ++gg) { S1 += sd1[gg][tid]; S2 += sd2[gg][tid]; }
        double mean = S1 / NPIX;
        double var = S2 / NPIX - mean * mean;
        double sc = (double)gamma[tid] / sqrt(var + BN_EPS);
        ws[SCALE_OFF + tid] = (float)sc;
        ws[SHIFT_OFF + tid] = (float)((double)beta[tid] - mean * sc);
    }
}

// ============ kC: kern[b,k,h,w] = b2 + w2 * relu(t*scale+shift) ============
__global__ __launch_bounds__(256) void kC_kern(const float* __restrict__ w2,
                                               const float* __restrict__ b2,
                                               float* __restrict__ ws) {
    __shared__ float s_t[CRED * W];
    __shared__ float s_w2[KK * CRED];
    int tid = threadIdx.x;
    int h = blockIdx.x, b = blockIdx.y;
    for (int i = tid; i < KK * CRED; i += 256) s_w2[i] = w2[i];
    const float* scale = ws + SCALE_OFF;
    const float* shift = ws + SHIFT_OFF;
    for (int i = tid; i < CRED * W; i += 256) {
        int r = i / W, w = i - r * W;
        float v = ws[T_OFF + ((size_t)b * CRED + r) * P + h * W + w];
        v = fmaf(v, scale[r], shift[r]);
        s_t[r * W + w] = fmaxf(v, 0.f);
    }
    __syncthreads();
    for (int i = tid; i < KK * W; i += 256) {
        int k = i / W, w = i - k * W;
        float acc = b2[k];
#pragma unroll
        for (int r = 0; r < CRED; ++r)
            acc = fmaf(s_w2[k * CRED + r], s_t[r * W + w], acc);
        ws[KERN_OFF + ((size_t)b * KK + k) * P + h * W + w] = acc;
    }
}

// ============ kD: involution, thread-per-pixel, kern in regs, 4-row tile ============
// grid (112, 8): blockIdx.x = b*14 + ht  (112%8==0 -> all z of same hb share an XCD)
//                blockIdx.y = z (channel group of 16)
__global__ __launch_bounds__(256) void kD_inv(const float* __restrict__ x,
                                              const float* __restrict__ ws,
                                              float* __restrict__ out) {
    __shared__ float s_x0[10 * 64];
    __shared__ float s_x1[10 * 64];
    int tid = threadIdx.x;
    int hb = blockIdx.x;
    int z  = blockIdx.y;
    int b = hb / 14, ht = hb - b * 14;
    int h0 = ht * 4;
    int th = tid >> 6;        // wave id == output row within tile
    int w  = tid & 63;        // pixel column (active < 56)
    int wl = min(w, W - 1);

    float kr[KK];
    {
        const float* kb = ws + KERN_OFF + (size_t)b * KK * P + (size_t)(h0 + th) * W + wl;
#pragma unroll
        for (int k = 0; k < KK; ++k) kr[k] = kb[(size_t)k * P];
    }

    // per-thread staging slots (addresses independent of channel)
    int off0, off1, off2 = 0, v0, v1, v2 = 0;
    {
        int i = tid;
        int row = i >> 6, col = i & 63;
        int hh = h0 - 3 + row, ww = col - 3;
        v0 = ((unsigned)hh < H && (unsigned)ww < W);
        off0 = hh * W + ww;
        i = tid + 256;
        row = i >> 6; col = i & 63; hh = h0 - 3 + row; ww = col - 3;
        v1 = ((unsigned)hh < H && (unsigned)ww < W);
        off1 = hh * W + ww;
        i = tid + 512;
        if (i < 640) {
            row = i >> 6; col = i & 63; hh = h0 - 3 + row; ww = col - 3;
            v2 = ((unsigned)hh < H && (unsigned)ww < W);
            off2 = hh * W + ww;
        }
    }
    int cbase = z * 16;
    {   // prologue: stage channel cbase into s_x0
        const float* xc = x + ((size_t)b * C + cbase) * P;
        s_x0[tid]       = v0 ? xc[off0] : 0.f;
        s_x0[tid + 256] = v1 ? xc[off1] : 0.f;
        if (tid < 128) s_x0[tid + 512] = v2 ? xc[off2] : 0.f;
    }
#pragma unroll 2
    for (int cc = 0; cc < 16; ++cc) {
        __syncthreads();
        const float* s_cur = (cc & 1) ? s_x1 : s_x0;
        float* s_nxt = (cc & 1) ? s_x0 : s_x1;
        // issue next channel's global loads early (latency hidden by compute)
        float n0 = 0.f, n1 = 0.f, n2 = 0.f;
        if (cc + 1 < 16) {
            const float* xc = x + ((size_t)b * C + cbase + cc + 1) * P;
            n0 = v0 ? xc[off0] : 0.f;
            n1 = v1 ? xc[off1] : 0.f;
            if (tid < 128) n2 = v2 ? xc[off2] : 0.f;
        }
        if (w < W) {
            const float* xs = s_cur + th * 64 + w;
            float acc = 0.f;
#pragma unroll
            for (int i = 0; i < K; ++i)
#pragma unroll
                for (int j = 0; j < K; ++j)
                    acc = fmaf(kr[i * 7 + j], xs[i * 64 + j], acc);
            out[((size_t)b * C + cbase + cc) * P + (size_t)(h0 + th) * W + w] = acc;
        }
        if (cc + 1 < 16) {
            s_nxt[tid]       = n0;
            s_nxt[tid + 256] = n1;
            if (tid < 128) s_nxt[tid + 512] = n2;
        }
    }
}

// ===================== fallback (round-1 proven, needs only 3.2MB ws) =====================
__global__ __launch_bounds__(256) void k1_conv1(const float* __restrict__ x,
                                                const float* __restrict__ w1,
                                                const float* __restrict__ b1,
                                                float* __restrict__ t) {
    __shared__ float s_w1t[C * CRED];
    int tid = threadIdx.x;
    for (int i = tid; i < C * CRED; i += 256) {
        int c = i >> 5, r = i & 31;
        s_w1t[i] = w1[r * C + c];
    }
    __syncthreads();
    int b = blockIdx.y;
    int p = blockIdx.x * 256 + tid;
    if (p >= P) return;
    float acc[CRED];
#pragma unroll
    for (int r = 0; r < CRED; ++r) acc[r] = 0.f;
    const float* xb = x + (size_t)b * C * P + p;
    for (int c = 0; c < C; ++c) {
        float xv = xb[(size_t)c * P];
#pragma unroll
        for (int r = 0; r < CRED; ++r)
            acc[r] = fmaf(s_w1t[c * CRED + r], xv, acc[r]);
    }
    float* tb = t + (size_t)b * CRED * P + p;
#pragma unroll
    for (int r = 0; r < CRED; ++r)
        tb[(size_t)r * P] = acc[r] + b1[r];
}

__global__ __launch_bounds__(256) void k2_bnstats(const float* __restrict__ t,
                                                  const float* __restrict__ gamma,
                                                  const float* __restrict__ beta,
                                                  float* __restrict__ scale,
                                                  float* __restrict__ shift) {
    int r = blockIdx.x;
    int tid = threadIdx.x;
    double s = 0.0, s2 = 0.0;
    for (int i = tid; i < NPIX; i += 256) {
        int b = i / P, p = i - b * P;
        float v = t[((size_t)b * CRED + r) * P + p];
        s += v;
        s2 += (double)v * v;
    }
    __shared__ double ls[256], ls2[256];
    ls[tid] = s; ls2[tid] = s2;
    __syncthreads();
    for (int off = 128; off > 0; off >>= 1) {
        if (tid < off) { ls[tid] += ls[tid + off]; ls2[tid] += ls2[tid + off]; }
        __syncthreads();
    }
    if (tid == 0) {
        double mean = ls[0] / NPIX;
        double var = ls2[0] / NPIX - mean * mean;
        double sc = (double)gamma[r] / sqrt(var + BN_EPS);
        scale[r] = (float)sc;
        shift[r] = (float)((double)beta[r] - mean * sc);
    }
}

__global__ __launch_bounds__(256) void k3_involution(const float* __restrict__ x,
                                                     const float* __restrict__ t,
                                                     const float* __restrict__ scale,
                                                     const float* __restrict__ shift,
                                                     const float* __restrict__ w2,
                                                     const float* __restrict__ b2,
                                                     float* __restrict__ out) {
    int h = blockIdx.x;
    int b = blockIdx.y;
    int z = blockIdx.z;
    int tid = threadIdx.x;
    __shared__ float s_w2[KK * CRED];
    __shared__ float s_t[CRED][W];
    __shared__ float s_kern[KK][W];
    __shared__ float s_x[4][K][64];
    for (int i = tid; i < KK * CRED; i += 256) s_w2[i] = w2[i];
    for (int i = tid; i < CRED * W; i += 256) {
        int r = i / W, w = i - r * W;
        float v = t[((size_t)b * CRED + r) * P + h * W + w];
        v = fmaf(v, scale[r], shift[r]);
        s_t[r][w] = fmaxf(v, 0.f);
    }
    __syncthreads();
    for (int i = tid; i < KK * W; i += 256) {
        int k = i / W, w = i - k * W;
        float acc = b2[k];
#pragma unroll
        for (int r = 0; r < CRED; ++r)
            acc = fmaf(s_w2[k * CRED + r], s_t[r][w], acc);
        s_kern[k][w] = acc;
    }
    __syncthreads();
    int w = tid % W;
    int c4 = tid / W;
    float kr[KK];
#pragma unroll
    for (int k = 0; k < KK; ++k) kr[k] = s_kern[k][w];
    int cbase = z * (C / 2);
    for (int cg = cbase; cg < cbase + C / 2; cg += 4) {
        for (int i = tid; i < 4 * K * 64; i += 256) {
            int col = i & 63;
            int rc = i >> 6;
            int cc = rc / K;
            int row = rc - cc * K;
            int hh = h - 3 + row;
            int ww = col - 3;
            float v = 0.f;
            if ((unsigned)hh < H && (unsigned)ww < W)
                v = x[(((size_t)b * C + cg + cc) * H + hh) * W + ww];
            s_x[cc][row][col] = v;
        }
        __syncthreads();
        if (tid < 4 * W) {
            float acc = 0.f;
#pragma unroll
            for (int i = 0; i < K; ++i)
#pragma unroll
                for (int j = 0; j < K; ++j)
                    acc = fmaf(kr[i * K + j], s_x[c4][i][w + j], acc);
            out[(((size_t)b * C + cg + c4) * H + h) * W + w] = acc;
        }
        __syncthreads();
    }
}

extern "C" void kernel_launch(void* const* d_in, const int* in_sizes, int n_in,
                              void* d_out, int out_size, void* d_ws, size_t ws_size,
                              hipStream_t stream) {
    const float* x     = (const float*)d_in[0];
    const float* w1    = (const float*)d_in[1];
    const float* b1    = (const float*)d_in[2];
    const float* gamma = (const float*)d_in[3];
    const float* beta  = (const float*)d_in[4];
    const float* w2    = (const float*)d_in[5];
    const float* b2    = (const float*)d_in[6];
    float* out = (float*)d_out;
    float* ws  = (float*)d_ws;

    if (ws_size >= WS_NEED) {
        dim3 gA(25, B);
        kA_conv1<<<gA, 256, 0, stream>>>(x, w1, b1, ws);
        kB_bnfin<<<1, 256, 0, stream>>>(gamma, beta, ws);
        dim3 gC(H, B);
        kC_kern<<<gC, 256, 0, stream>>>(w2, b2, ws);
        dim3 gD(112, 8);
        kD_inv<<<gD, 256, 0, stream>>>(x, ws, out);
    } else {
        float* t     = ws;
        float* scale = ws + FB_SCALE_OFF;
        float* shift = ws + FB_SHIFT_OFF;
        dim3 g1((P + 255) / 256, B);
        k1_conv1<<<g1, 256, 0, stream>>>(x, w1, b1, t);
        k2_bnstats<<<CRED, 256, 0, stream>>>(t, gamma, beta, scale, shift);
        dim3 g3(H, B, 2);
        k3_involution<<<g3, 256, 0, stream>>>(x, t, scale, shift, w2, b2, out);
    }
}

// Round 4
// 52.947 us; speedup vs baseline: 2.4573x; 1.3130x over previous
//
#include <hip/hip_runtime.h>

#define C 128
#define CRED 32
#define K 7
#define KK 49
#define H 56
#define W 56
#define P (H*W)        // 3136
#define B 8
#define NPIX (B*P)     // 25088
#define BN_EPS 1e-5

// ---------------- fast-path ws layout (floats) ----------------
#define T_OFF 0
#define T_SIZE (B*CRED*P)                 // 802816
#define KERN_OFF (T_OFF + T_SIZE)         // 802816
#define KERN_SIZE (B*KK*P)                // 1229312
#define NBLK_A (49*B)                     // 392 partial-sum blocks
#define PSUM_OFF (KERN_OFF + KERN_SIZE)   // 2032128
#define PSQ_OFF (PSUM_OFF + NBLK_A*CRED)
#define SS_OFF  (PSQ_OFF + NBLK_A*CRED)
#define SCALE_OFF SS_OFF
#define SHIFT_OFF (SS_OFF + CRED)
#define WS_NEED ((size_t)(SHIFT_OFF + CRED) * sizeof(float))

// fallback (round-1) layout
#define FB_SCALE_OFF T_SIZE
#define FB_SHIFT_OFF (T_SIZE + CRED)

// ============ kA: t = w1*x + b1 + per-block BN partial sums ============
// grid (49, B, 2): bx = 64-px tile, by = b, bz = rh (16-r half)
// block 256: px = tid&63 (wave==64 consecutive px), rq = tid>>6 -> 4 r per thread
__global__ __launch_bounds__(256) void kA_conv1(const float* __restrict__ x,
                                                const float* __restrict__ w1,
                                                const float* __restrict__ b1,
                                                float* __restrict__ ws) {
    __shared__ float s_w1t[C][16];   // [c][rr] for this r-half
    int tid = threadIdx.x;
    int bx = blockIdx.x;
    int b  = blockIdx.y;
    int rh = blockIdx.z;
    for (int i = tid; i < C * 16; i += 256) {
        int c = i >> 4, rr = i & 15;
        s_w1t[c][rr] = w1[(rh * 16 + rr) * C + c];
    }
    __syncthreads();
    int px = tid & 63;
    int rq = tid >> 6;                 // 0..3
    int p  = bx * 64 + px;             // always < P (49*64 == P)
    int rbase = rh * 16 + rq * 4;
    const float* xb = x + (size_t)b * C * P + p;

    float a0 = 0.f, a1 = 0.f, a2 = 0.f, a3 = 0.f;
#pragma unroll 8
    for (int c = 0; c < C; ++c) {
        float xv = xb[(size_t)c * P];
        float4 wv = *(const float4*)&s_w1t[c][rq * 4];   // wave-uniform broadcast
        a0 = fmaf(wv.x, xv, a0);
        a1 = fmaf(wv.y, xv, a1);
        a2 = fmaf(wv.z, xv, a2);
        a3 = fmaf(wv.w, xv, a3);
    }
    a0 += b1[rbase + 0];
    a1 += b1[rbase + 1];
    a2 += b1[rbase + 2];
    a3 += b1[rbase + 3];

    float* tb = ws + T_OFF + (size_t)b * CRED * P + p;
    tb[(size_t)(rbase + 0) * P] = a0;
    tb[(size_t)(rbase + 1) * P] = a1;
    tb[(size_t)(rbase + 2) * P] = a2;
    tb[(size_t)(rbase + 3) * P] = a3;

    // exact fixed-tree wave reduction (wave == 64 px of this tile, 4 unique r)
    float s0 = a0, s1 = a1, s2 = a2, s3 = a3;
    float q0 = a0 * a0, q1 = a1 * a1, q2 = a2 * a2, q3 = a3 * a3;
#pragma unroll
    for (int off = 32; off; off >>= 1) {
        s0 += __shfl_xor(s0, off);  q0 += __shfl_xor(q0, off);
        s1 += __shfl_xor(s1, off);  q1 += __shfl_xor(q1, off);
        s2 += __shfl_xor(s2, off);  q2 += __shfl_xor(q2, off);
        s3 += __shfl_xor(s3, off);  q3 += __shfl_xor(q3, off);
    }
    if ((tid & 63) == 0) {
        int blk = b * 49 + bx;
        float* psum = ws + PSUM_OFF + (size_t)blk * CRED + rbase;
        float* psq  = ws + PSQ_OFF  + (size_t)blk * CRED + rbase;
        psum[0] = s0; psum[1] = s1; psum[2] = s2; psum[3] = s3;
        psq[0]  = q0; psq[1]  = q1; psq[2]  = q2; psq[3]  = q3;
    }
}

// ============ kB: finalize BN stats -> scale/shift (1 block, deterministic) ============
__global__ __launch_bounds__(256) void kB_bnfin(const float* __restrict__ gamma,
                                                const float* __restrict__ beta,
                                                float* __restrict__ ws) {
    __shared__ double sd1[8][CRED];
    __shared__ double sd2[8][CRED];
    int tid = threadIdx.x;
    int r = tid & 31, g = tid >> 5;
    double s1 = 0.0, s2 = 0.0;
    for (int i = g * 49; i < g * 49 + 49; ++i) {
        s1 += (double)ws[PSUM_OFF + i * CRED + r];
        s2 += (double)ws[PSQ_OFF + i * CRED + r];
    }
    sd1[g][r] = s1; sd2[g][r] = s2;
    __syncthreads();
    if (tid < CRED) {
        double S1 = 0.0, S2 = 0.0;
        for (int gg = 0; gg < 8; ++gg) { S1 += sd1[gg][tid]; S2 += sd2[gg][tid]; }
        double mean = S1 / NPIX;
        double var = S2 / NPIX - mean * mean;
        double sc = (double)gamma[tid] / sqrt(var + BN_EPS);
        ws[SCALE_OFF + tid] = (float)sc;
        ws[SHIFT_OFF + tid] = (float)((double)beta[tid] - mean * sc);
    }
}

// ============ kC: kern[b,k,h,w] = b2 + w2 * relu(t*scale+shift) ============
__global__ __launch_bounds__(256) void kC_kern(const float* __restrict__ w2,
                                               const float* __restrict__ b2,
                                               float* __restrict__ ws) {
    __shared__ float s_t[CRED * W];
    __shared__ float s_w2[KK * CRED];
    int tid = threadIdx.x;
    int h = blockIdx.x, b = blockIdx.y;
    for (int i = tid; i < KK * CRED; i += 256) s_w2[i] = w2[i];
    const float* scale = ws + SCALE_OFF;
    const float* shift = ws + SHIFT_OFF;
    for (int i = tid; i < CRED * W; i += 256) {
        int r = i / W, w = i - r * W;
        float v = ws[T_OFF + ((size_t)b * CRED + r) * P + h * W + w];
        v = fmaf(v, scale[r], shift[r]);
        s_t[r * W + w] = fmaxf(v, 0.f);
    }
    __syncthreads();
    for (int i = tid; i < KK * W; i += 256) {
        int k = i / W, w = i - k * W;
        float acc = b2[k];
#pragma unroll
        for (int r = 0; r < CRED; ++r)
            acc = fmaf(s_w2[k * CRED + r], s_t[r * W + w], acc);
        ws[KERN_OFF + ((size_t)b * KK + k) * P + h * W + w] = acc;
    }
}

// ============ kD: involution, thread-per-pixel, kern in regs, 4-row tile ============
__global__ __launch_bounds__(256) void kD_inv(const float* __restrict__ x,
                                              const float* __restrict__ ws,
                                              float* __restrict__ out) {
    __shared__ float s_x0[10 * 64];
    __shared__ float s_x1[10 * 64];
    int tid = threadIdx.x;
    int hb = blockIdx.x;
    int z  = blockIdx.y;
    int b = hb / 14, ht = hb - b * 14;
    int h0 = ht * 4;
    int th = tid >> 6;
    int w  = tid & 63;
    int wl = min(w, W - 1);

    float kr[KK];
    {
        const float* kb = ws + KERN_OFF + (size_t)b * KK * P + (size_t)(h0 + th) * W + wl;
#pragma unroll
        for (int k = 0; k < KK; ++k) kr[k] = kb[(size_t)k * P];
    }

    int off0, off1, off2 = 0, v0, v1, v2 = 0;
    {
        int i = tid;
        int row = i >> 6, col = i & 63;
        int hh = h0 - 3 + row, ww = col - 3;
        v0 = ((unsigned)hh < H && (unsigned)ww < W);
        off0 = hh * W + ww;
        i = tid + 256;
        row = i >> 6; col = i & 63; hh = h0 - 3 + row; ww = col - 3;
        v1 = ((unsigned)hh < H && (unsigned)ww < W);
        off1 = hh * W + ww;
        i = tid + 512;
        if (i < 640) {
            row = i >> 6; col = i & 63; hh = h0 - 3 + row; ww = col - 3;
            v2 = ((unsigned)hh < H && (unsigned)ww < W);
            off2 = hh * W + ww;
        }
    }
    int cbase = z * 16;
    {
        const float* xc = x + ((size_t)b * C + cbase) * P;
        s_x0[tid]       = v0 ? xc[off0] : 0.f;
        s_x0[tid + 256] = v1 ? xc[off1] : 0.f;
        if (tid < 128) s_x0[tid + 512] = v2 ? xc[off2] : 0.f;
    }
#pragma unroll 2
    for (int cc = 0; cc < 16; ++cc) {
        __syncthreads();
        const float* s_cur = (cc & 1) ? s_x1 : s_x0;
        float* s_nxt = (cc & 1) ? s_x0 : s_x1;
        float n0 = 0.f, n1 = 0.f, n2 = 0.f;
        if (cc + 1 < 16) {
            const float* xc = x + ((size_t)b * C + cbase + cc + 1) * P;
            n0 = v0 ? xc[off0] : 0.f;
            n1 = v1 ? xc[off1] : 0.f;
            if (tid < 128) n2 = v2 ? xc[off2] : 0.f;
        }
        if (w < W) {
            const float* xs = s_cur + th * 64 + w;
            float acc = 0.f;
#pragma unroll
            for (int i = 0; i < K; ++i)
#pragma unroll
                for (int j = 0; j < K; ++j)
                    acc = fmaf(kr[i * 7 + j], xs[i * 64 + j], acc);
            out[((size_t)b * C + cbase + cc) * P + (size_t)(h0 + th) * W + w] = acc;
        }
        if (cc + 1 < 16) {
            s_nxt[tid]       = n0;
            s_nxt[tid + 256] = n1;
            if (tid < 128) s_nxt[tid + 512] = n2;
        }
    }
}

// ===================== fallback (round-1 proven, needs only 3.2MB ws) =====================
__global__ __launch_bounds__(256) void k1_conv1(const float* __restrict__ x,
                                                const float* __restrict__ w1,
                                                const float* __restrict__ b1,
                                                float* __restrict__ t) {
    __shared__ float s_w1t[C * CRED];
    int tid = threadIdx.x;
    for (int i = tid; i < C * CRED; i += 256) {
        int c = i >> 5, r = i & 31;
        s_w1t[i] = w1[r * C + c];
    }
    __syncthreads();
    int b = blockIdx.y;
    int p = blockIdx.x * 256 + tid;
    if (p >= P) return;
    float acc[CRED];
#pragma unroll
    for (int r = 0; r < CRED; ++r) acc[r] = 0.f;
    const float* xb = x + (size_t)b * C * P + p;
    for (int c = 0; c < C; ++c) {
        float xv = xb[(size_t)c * P];
#pragma unroll
        for (int r = 0; r < CRED; ++r)
            acc[r] = fmaf(s_w1t[c * CRED + r], xv, acc[r]);
    }
    float* tb = t + (size_t)b * CRED * P + p;
#pragma unroll
    for (int r = 0; r < CRED; ++r)
        tb[(size_t)r * P] = acc[r] + b1[r];
}

__global__ __launch_bounds__(256) void k2_bnstats(const float* __restrict__ t,
                                                  const float* __restrict__ gamma,
                                                  const float* __restrict__ beta,
                                                  float* __restrict__ scale,
                                                  float* __restrict__ shift) {
    int r = blockIdx.x;
    int tid = threadIdx.x;
    double s = 0.0, s2 = 0.0;
    for (int i = tid; i < NPIX; i += 256) {
        int b = i / P, p = i - b * P;
        float v = t[((size_t)b * CRED + r) * P + p];
        s += v;
        s2 += (double)v * v;
    }
    __shared__ double ls[256], ls2[256];
    ls[tid] = s; ls2[tid] = s2;
    __syncthreads();
    for (int off = 128; off > 0; off >>= 1) {
        if (tid < off) { ls[tid] += ls[tid + off]; ls2[tid] += ls2[tid + off]; }
        __syncthreads();
    }
    if (tid == 0) {
        double mean = ls[0] / NPIX;
        double var = ls2[0] / NPIX - mean * mean;
        double sc = (double)gamma[r] / sqrt(var + BN_EPS);
        scale[r] = (float)sc;
        shift[r] = (float)((double)beta[r] - mean * sc);
    }
}

__global__ __launch_bounds__(256) void k3_involution(const float* __restrict__ x,
                                                     const float* __restrict__ t,
                                                     const float* __restrict__ scale,
                                                     const float* __restrict__ shift,
                                                     const float* __restrict__ w2,
                                                     const float* __restrict__ b2,
                                                     float* __restrict__ out) {
    int h = blockIdx.x;
    int b = blockIdx.y;
    int z = blockIdx.z;
    int tid = threadIdx.x;
    __shared__ float s_w2[KK * CRED];
    __shared__ float s_t[CRED * W];
    __shared__ float s_kern[KK][W];
    __shared__ float s_x[4][K][64];
    for (int i = tid; i < KK * CRED; i += 256) s_w2[i] = w2[i];
    for (int i = tid; i < CRED * W; i += 256) {
        int r = i / W, w = i - r * W;
        float v = t[((size_t)b * CRED + r) * P + h * W + w];
        v = fmaf(v, scale[r], shift[r]);
        s_t[r * W + w] = fmaxf(v, 0.f);
    }
    __syncthreads();
    for (int i = tid; i < KK * W; i += 256) {
        int k = i / W, w = i - k * W;
        float acc = b2[k];
#pragma unroll
        for (int r = 0; r < CRED; ++r)
            acc = fmaf(s_w2[k * CRED + r], s_t[r * W + w], acc);
        s_kern[k][w] = acc;
    }
    __syncthreads();
    int w = tid % W;
    int c4 = tid / W;
    float kr[KK];
#pragma unroll
    for (int k = 0; k < KK; ++k) kr[k] = s_kern[k][w];
    int cbase = z * (C / 2);
    for (int cg = cbase; cg < cbase + C / 2; cg += 4) {
        for (int i = tid; i < 4 * K * 64; i += 256) {
            int col = i & 63;
            int rc = i >> 6;
            int cc = rc / K;
            int row = rc - cc * K;
            int hh = h - 3 + row;
            int ww = col - 3;
            float v = 0.f;
            if ((unsigned)hh < H && (unsigned)ww < W)
                v = x[(((size_t)b * C + cg + cc) * H + hh) * W + ww];
            s_x[cc][row][col] = v;
        }
        __syncthreads();
        if (tid < 4 * W) {
            float acc = 0.f;
#pragma unroll
            for (int i = 0; i < K; ++i)
#pragma unroll
                for (int j = 0; j < K; ++j)
                    acc = fmaf(kr[i * K + j], s_x[c4][i][w + j], acc);
            out[(((size_t)b * C + cg + c4) * H + h) * W + w] = acc;
        }
        __syncthreads();
    }
}

extern "C" void kernel_launch(void* const* d_in, const int* in_sizes, int n_in,
                              void* d_out, int out_size, void* d_ws, size_t ws_size,
                              hipStream_t stream) {
    const float* x     = (const float*)d_in[0];
    const float* w1    = (const float*)d_in[1];
    const float* b1    = (const float*)d_in[2];
    const float* gamma = (const float*)d_in[3];
    const float* beta  = (const float*)d_in[4];
    const float* w2    = (const float*)d_in[5];
    const float* b2    = (const float*)d_in[6];
    float* out = (float*)d_out;
    float* ws  = (float*)d_ws;

    if (ws_size >= WS_NEED) {
        dim3 gA(49, B, 2);
        kA_conv1<<<gA, 256, 0, stream>>>(x, w1, b1, ws);
        kB_bnfin<<<1, 256, 0, stream>>>(gamma, beta, ws);
        dim3 gC(H, B);
        kC_kern<<<gC, 256, 0, stream>>>(w2, b2, ws);
        dim3 gD(112, 8);
        kD_inv<<<gD, 256, 0, stream>>>(x, ws, out);
    } else {
        float* t     = ws;
        float* scale = ws + FB_SCALE_OFF;
        float* shift = ws + FB_SHIFT_OFF;
        dim3 g1((P + 255) / 256, B);
        k1_conv1<<<g1, 256, 0, stream>>>(x, w1, b1, t);
        k2_bnstats<<<CRED, 256, 0, stream>>>(t, gamma, beta, scale, shift);
        dim3 g3(H, B, 2);
        k3_involution<<<g3, 256, 0, stream>>>(x, t, scale, shift, w2, b2, out);
    }
}

// Round 5
// 44.423 us; speedup vs baseline: 2.9288x; 1.1919x over previous
//
#include <hip/hip_runtime.h>

#define C 128
#define CRED 32
#define K 7
#define KK 49
#define H 56
#define W 56
#define P (H*W)        // 3136
#define B 8
#define NPIX (B*P)     // 25088
#define BN_EPS 1e-5

// ---------------- fast-path ws layout (floats) ----------------
#define T_OFF 0
#define T_SIZE (B*CRED*P)                 // 802816
#define KERN_OFF (T_OFF + T_SIZE)
#define KERN_SIZE (B*KK*P)                // 1229312
#define NBLK_A (49*B)                     // 392
#define PSUM_OFF (KERN_OFF + KERN_SIZE)
#define PSQ_OFF (PSUM_OFF + NBLK_A*CRED)
#define SS_OFF  (PSQ_OFF + NBLK_A*CRED)
#define SCALE_OFF SS_OFF
#define SHIFT_OFF (SS_OFF + CRED)
#define WS_NEED ((size_t)(SHIFT_OFF + CRED) * sizeof(float))

// fallback layout
#define FB_SCALE_OFF T_SIZE
#define FB_SHIFT_OFF (T_SIZE + CRED)

// ============ kA v3: t = w1*x + b1 + BN partials. No LDS; w1 via uniform scalar loads ============
// grid (49, B), block 256 = 64 px × 4 waves; wave rq owns 8 r.
__global__ __launch_bounds__(256) void kA_conv1(const float* __restrict__ x,
                                                const float* __restrict__ w1,
                                                const float* __restrict__ b1,
                                                float* __restrict__ ws) {
    int tid = threadIdx.x;
    int bx = blockIdx.x;
    int b  = blockIdx.y;
    int px = tid & 63;
    int p  = bx * 64 + px;                       // < P (49*64 == P)
    int ru8 = __builtin_amdgcn_readfirstlane((tid >> 6) * 8);   // wave-uniform r base
    const float* __restrict__ wq = w1 + (size_t)ru8 * C;        // uniform -> s_load
    const float* xb = x + (size_t)b * C * P + p;

    float acc[8];
#pragma unroll
    for (int u = 0; u < 8; ++u) acc[u] = 0.f;
#pragma unroll 8
    for (int c = 0; c < C; ++c) {
        float xv = xb[(size_t)c * P];
#pragma unroll
        for (int u = 0; u < 8; ++u)
            acc[u] = fmaf(wq[u * C + c], xv, acc[u]);
    }
#pragma unroll
    for (int u = 0; u < 8; ++u) acc[u] += b1[ru8 + u];

    float* tb = ws + T_OFF + (size_t)b * CRED * P + p;
#pragma unroll
    for (int u = 0; u < 8; ++u)
        tb[(size_t)(ru8 + u) * P] = acc[u];

    // exact fixed-tree wave reduction (wave == 64 px, 8 unique r per wave)
    float s[8], q[8];
#pragma unroll
    for (int u = 0; u < 8; ++u) { s[u] = acc[u]; q[u] = acc[u] * acc[u]; }
#pragma unroll
    for (int off = 32; off; off >>= 1) {
#pragma unroll
        for (int u = 0; u < 8; ++u) {
            s[u] += __shfl_xor(s[u], off);
            q[u] += __shfl_xor(q[u], off);
        }
    }
    if (px == 0) {
        int blk = b * 49 + bx;
        float* psum = ws + PSUM_OFF + (size_t)blk * CRED + ru8;
        float* psq  = ws + PSQ_OFF  + (size_t)blk * CRED + ru8;
#pragma unroll
        for (int u = 0; u < 8; ++u) { psum[u] = s[u]; psq[u] = q[u]; }
    }
}

// ============ kB: finalize BN stats -> scale/shift (1 block, deterministic) ============
__global__ __launch_bounds__(256) void kB_bnfin(const float* __restrict__ gamma,
                                                const float* __restrict__ beta,
                                                float* __restrict__ ws) {
    __shared__ double sd1[8][CRED];
    __shared__ double sd2[8][CRED];
    int tid = threadIdx.x;
    int r = tid & 31, g = tid >> 5;
    double s1 = 0.0, s2 = 0.0;
    for (int i = g * 49; i < g * 49 + 49; ++i) {
        s1 += (double)ws[PSUM_OFF + i * CRED + r];
        s2 += (double)ws[PSQ_OFF + i * CRED + r];
    }
    sd1[g][r] = s1; sd2[g][r] = s2;
    __syncthreads();
    if (tid < CRED) {
        double S1 = 0.0, S2 = 0.0;
        for (int gg = 0; gg < 8; ++gg) { S1 += sd1[gg][tid]; S2 += sd2[gg][tid]; }
        double mean = S1 / NPIX;
        double var = S2 / NPIX - mean * mean;
        double sc = (double)gamma[tid] / sqrt(var + BN_EPS);
        ws[SCALE_OFF + tid] = (float)sc;
        ws[SHIFT_OFF + tid] = (float)((double)beta[tid] - mean * sc);
    }
}

// ============ kC v2: kern[b,k,h,w] = b2 + w2 * relu(t*scale+shift); float4 s_t reads ============
// grid (H, B), block 256. thread computes 4 adjacent w for one k.
__global__ __launch_bounds__(256) void kC_kern(const float* __restrict__ w2,
                                               const float* __restrict__ b2,
                                               float* __restrict__ ws) {
    __shared__ float s_t[CRED * W];        // 32x56
    __shared__ float s_w2[KK * 33];        // padded: [k][33] kills dk-bank-conflict
    int tid = threadIdx.x;
    int h = blockIdx.x, b = blockIdx.y;
    for (int i = tid; i < KK * CRED; i += 256) {
        int k = i >> 5, r = i & 31;
        s_w2[k * 33 + r] = w2[i];
    }
    const float* scale = ws + SCALE_OFF;
    const float* shift = ws + SHIFT_OFF;
    for (int i = tid; i < CRED * W; i += 256) {
        int r = i / W, w = i - r * W;
        float v = ws[T_OFF + ((size_t)b * CRED + r) * P + h * W + w];
        v = fmaf(v, scale[r], shift[r]);
        s_t[r * W + w] = fmaxf(v, 0.f);
    }
    __syncthreads();
    for (int i = tid; i < KK * 14; i += 256) {   // 686 (k, w-quad) tasks
        int k = i / 14, w0 = (i - k * 14) * 4;
        float bb = b2[k];
        float a0 = bb, a1 = bb, a2 = bb, a3 = bb;
#pragma unroll
        for (int r = 0; r < CRED; ++r) {
            float4 tv = *(const float4*)&s_t[r * W + w0];   // 16B-aligned (W*4%16==0, w0%4==0)
            float wv = s_w2[k * 33 + r];
            a0 = fmaf(wv, tv.x, a0);
            a1 = fmaf(wv, tv.y, a1);
            a2 = fmaf(wv, tv.z, a2);
            a3 = fmaf(wv, tv.w, a3);
        }
        float4 o = {a0, a1, a2, a3};
        *(float4*)&ws[KERN_OFF + ((size_t)b * KK + k) * P + h * W + w0] = o;
    }
}

// ============ kD v3: involution, 4-channel float4-interleaved LDS, 8-row tiles ============
// grid (56, 8): bx = b*7 + ht, by = z (16-ch group). block 448 = 8 rows x 56 cols.
#define TH 8
#define XROWS 14          // TH + 6
#define XPITCH 68         // padded (bank-neutral vs 64)
__global__ __launch_bounds__(448) void kD_inv(const float* __restrict__ x,
                                              const float* __restrict__ ws,
                                              float* __restrict__ out) {
    __shared__ float4 s_x[2][XROWS * XPITCH];   // 2 x 14 x 68 x 16B = 30464 B
    int tid = threadIdx.x;
    int bx = blockIdx.x;
    int z  = blockIdx.y;
    int b = bx / 7, ht = bx - b * 7;
    int h0 = ht * TH;
    int orow = tid / W;                   // 0..7
    int ocol = tid - orow * W;            // 0..55
    int sbase = orow * XPITCH + ocol;

    // per-pixel kernel -> 49 regs (coalesced: h0*W + tid is contiguous in tid)
    float kr[KK];
    {
        const float* kb = ws + KERN_OFF + (size_t)b * KK * P + (size_t)h0 * W + tid;
#pragma unroll
        for (int k = 0; k < KK; ++k) kr[k] = kb[(size_t)k * P];
    }

    // two staging positions per thread: q, q+448 in [0, 14*64)
    int slot0, slot1, off0, off1, v0, v1;
    {
        int q = tid;
        int row = q >> 6, col = q & 63;
        int hh = h0 - 3 + row, ww = col - 3;
        v0 = ((unsigned)hh < H && (unsigned)ww < W);
        off0 = hh * W + ww;
        slot0 = row * XPITCH + col;
        q = tid + 448;
        row = q >> 6; col = q & 63;
        hh = h0 - 3 + row; ww = col - 3;
        v1 = ((unsigned)hh < H && (unsigned)ww < W);
        off1 = hh * W + ww;
        slot1 = row * XPITCH + col;
    }

    int cg0 = z * 16;
    const size_t xbase = ((size_t)b * C + cg0) * P;
    {   // prologue: stage channels cg0..cg0+3 into buffer 0
        const float* xc = x + xbase;
        float4 f0, f1;
        f0.x = v0 ? xc[off0] : 0.f;  f0.y = v0 ? xc[P + off0] : 0.f;
        f0.z = v0 ? xc[2 * P + off0] : 0.f;  f0.w = v0 ? xc[3 * P + off0] : 0.f;
        f1.x = v1 ? xc[off1] : 0.f;  f1.y = v1 ? xc[P + off1] : 0.f;
        f1.z = v1 ? xc[2 * P + off1] : 0.f;  f1.w = v1 ? xc[3 * P + off1] : 0.f;
        s_x[0][slot0] = f0;
        s_x[0][slot1] = f1;
    }

    for (int it = 0; it < 4; ++it) {
        __syncthreads();
        // T14: issue next group's loads before compute
        float4 n0, n1;
        if (it < 3) {
            const float* xc = x + xbase + (size_t)(it + 1) * 4 * P;
            n0.x = v0 ? xc[off0] : 0.f;  n0.y = v0 ? xc[P + off0] : 0.f;
            n0.z = v0 ? xc[2 * P + off0] : 0.f;  n0.w = v0 ? xc[3 * P + off0] : 0.f;
            n1.x = v1 ? xc[off1] : 0.f;  n1.y = v1 ? xc[P + off1] : 0.f;
            n1.z = v1 ? xc[2 * P + off1] : 0.f;  n1.w = v1 ? xc[3 * P + off1] : 0.f;
        }
        const float4* xs = s_x[it & 1] + sbase;
        float a0 = 0.f, a1 = 0.f, a2 = 0.f, a3 = 0.f;
#pragma unroll
        for (int i = 0; i < K; ++i) {
#pragma unroll
            for (int j = 0; j < K; ++j) {
                float4 xv = xs[i * XPITCH + j];     // one b128 feeds 4 channels
                float kv = kr[i * 7 + j];
                a0 = fmaf(kv, xv.x, a0);
                a1 = fmaf(kv, xv.y, a1);
                a2 = fmaf(kv, xv.z, a2);
                a3 = fmaf(kv, xv.w, a3);
            }
        }
        float* ob = out + xbase + (size_t)it * 4 * P + (size_t)h0 * W + tid;
        ob[0]     = a0;
        ob[P]     = a1;
        ob[2 * P] = a2;
        ob[3 * P] = a3;
        if (it < 3) {
            float4* nb = s_x[(it + 1) & 1];
            nb[slot0] = n0;
            nb[slot1] = n1;
        }
    }
}

// ===================== fallback (proven, needs only 3.3MB ws) =====================
__global__ __launch_bounds__(256) void k1_conv1(const float* __restrict__ x,
                                                const float* __restrict__ w1,
                                                const float* __restrict__ b1,
                                                float* __restrict__ t) {
    __shared__ float s_w1t[C * CRED];
    int tid = threadIdx.x;
    for (int i = tid; i < C * CRED; i += 256) {
        int c = i >> 5, r = i & 31;
        s_w1t[i] = w1[r * C + c];
    }
    __syncthreads();
    int b = blockIdx.y;
    int p = blockIdx.x * 256 + tid;
    if (p >= P) return;
    float acc[CRED];
#pragma unroll
    for (int r = 0; r < CRED; ++r) acc[r] = 0.f;
    const float* xb = x + (size_t)b * C * P + p;
    for (int c = 0; c < C; ++c) {
        float xv = xb[(size_t)c * P];
#pragma unroll
        for (int r = 0; r < CRED; ++r)
            acc[r] = fmaf(s_w1t[c * CRED + r], xv, acc[r]);
    }
    float* tb = t + (size_t)b * CRED * P + p;
#pragma unroll
    for (int r = 0; r < CRED; ++r)
        tb[(size_t)r * P] = acc[r] + b1[r];
}

__global__ __launch_bounds__(256) void k2_bnstats(const float* __restrict__ t,
                                                  const float* __restrict__ gamma,
                                                  const float* __restrict__ beta,
                                                  float* __restrict__ scale,
                                                  float* __restrict__ shift) {
    int r = blockIdx.x;
    int tid = threadIdx.x;
    double s = 0.0, s2 = 0.0;
    for (int i = tid; i < NPIX; i += 256) {
        int b = i / P, p = i - b * P;
        float v = t[((size_t)b * CRED + r) * P + p];
        s += v;
        s2 += (double)v * v;
    }
    __shared__ double ls[256], ls2[256];
    ls[tid] = s; ls2[tid] = s2;
    __syncthreads();
    for (int off = 128; off > 0; off >>= 1) {
        if (tid < off) { ls[tid] += ls[tid + off]; ls2[tid] += ls2[tid + off]; }
        __syncthreads();
    }
    if (tid == 0) {
        double mean = ls[0] / NPIX;
        double var = ls2[0] / NPIX - mean * mean;
        double sc = (double)gamma[r] / sqrt(var + BN_EPS);
        scale[r] = (float)sc;
        shift[r] = (float)((double)beta[r] - mean * sc);
    }
}

__global__ __launch_bounds__(256) void k3_involution(const float* __restrict__ x,
                                                     const float* __restrict__ t,
                                                     const float* __restrict__ scale,
                                                     const float* __restrict__ shift,
                                                     const float* __restrict__ w2,
                                                     const float* __restrict__ b2,
                                                     float* __restrict__ out) {
    int h = blockIdx.x;
    int b = blockIdx.y;
    int z = blockIdx.z;
    int tid = threadIdx.x;
    __shared__ float s_w2[KK * CRED];
    __shared__ float s_t[CRED * W];
    __shared__ float s_kern[KK][W];
    __shared__ float s_x[4][K][64];
    for (int i = tid; i < KK * CRED; i += 256) s_w2[i] = w2[i];
    for (int i = tid; i < CRED * W; i += 256) {
        int r = i / W, w = i - r * W;
        float v = t[((size_t)b * CRED + r) * P + h * W + w];
        v = fmaf(v, scale[r], shift[r]);
        s_t[r * W + w] = fmaxf(v, 0.f);
    }
    __syncthreads();
    for (int i = tid; i < KK * W; i += 256) {
        int k = i / W, w = i - k * W;
        float acc = b2[k];
#pragma unroll
        for (int r = 0; r < CRED; ++r)
            acc = fmaf(s_w2[k * CRED + r], s_t[r * W + w], acc);
        s_kern[k][w] = acc;
    }
    __syncthreads();
    int w = tid % W;
    int c4 = tid / W;
    float kr[KK];
#pragma unroll
    for (int k = 0; k < KK; ++k) kr[k] = s_kern[k][w];
    int cbase = z * (C / 2);
    for (int cg = cbase; cg < cbase + C / 2; cg += 4) {
        for (int i = tid; i < 4 * K * 64; i += 256) {
            int col = i & 63;
            int rc = i >> 6;
            int cc = rc / K;
            int row = rc - cc * K;
            int hh = h - 3 + row;
            int ww = col - 3;
            float v = 0.f;
            if ((unsigned)hh < H && (unsigned)ww < W)
                v = x[(((size_t)b * C + cg + cc) * H + hh) * W + ww];
            s_x[cc][row][col] = v;
        }
        __syncthreads();
        if (tid < 4 * W) {
            float acc = 0.f;
#pragma unroll
            for (int i = 0; i < K; ++i)
#pragma unroll
                for (int j = 0; j < K; ++j)
                    acc = fmaf(kr[i * K + j], s_x[c4][i][w + j], acc);
            out[(((size_t)b * C + cg + c4) * H + h) * W + w] = acc;
        }
        __syncthreads();
    }
}

extern "C" void kernel_launch(void* const* d_in, const int* in_sizes, int n_in,
                              void* d_out, int out_size, void* d_ws, size_t ws_size,
                              hipStream_t stream) {
    const float* x     = (const float*)d_in[0];
    const float* w1    = (const float*)d_in[1];
    const float* b1    = (const float*)d_in[2];
    const float* gamma = (const float*)d_in[3];
    const float* beta  = (const float*)d_in[4];
    const float* w2    = (const float*)d_in[5];
    const float* b2    = (const float*)d_in[6];
    float* out = (float*)d_out;
    float* ws  = (float*)d_ws;

    if (ws_size >= WS_NEED) {
        dim3 gA(49, B);
        kA_conv1<<<gA, 256, 0, stream>>>(x, w1, b1, ws);
        kB_bnfin<<<1, 256, 0, stream>>>(gamma, beta, ws);
        dim3 gC(H, B);
        kC_kern<<<gC, 256, 0, stream>>>(w2, b2, ws);
        dim3 gD(7 * B, 8);
        kD_inv<<<gD, 448, 0, stream>>>(x, ws, out);
    } else {
        float* t     = ws;
        float* scale = ws + FB_SCALE_OFF;
        float* shift = ws + FB_SHIFT_OFF;
        dim3 g1((P + 255) / 256, B);
        k1_conv1<<<g1, 256, 0, stream>>>(x, w1, b1, t);
        k2_bnstats<<<CRED, 256, 0, stream>>>(t, gamma, beta, scale, shift);
        dim3 g3(H, B, 2);
        k3_involution<<<g3, 256, 0, stream>>>(x, t, scale, shift, w2, b2, out);
    }
}